// Round 4
// baseline (214.883 us; speedup 1.0000x reference)
//
#include <hip/hip_runtime.h>
#include <math.h>

// ---------------- problem constants ----------------
#define NB 4
#define NH 96
#define NW 96
#define ND 768
#define NPIX (NH*NW)          // 9216
#define RR 3
#define NK 49
#define TS 16                 // tile 16x16 pixels
#define HL 22                 // halo 22x22
#define NVIS (HL*HL)          // 484 vis slots
#define NSLOT 740             // 484 vis + 256 rubin
#define LROW 40               // ushorts per slot (32 bf16 data + 8 pad = 80B)
#define ABASE (NVIS*LROW)     // rubin slots start here in lds
#define DCC 32                // K per chunk
#define NPASS 6               // ceil(740*8/1024) staging passes
#define TAU 0.1f
#define SCALE 0.03608439182435161f  // 1/sqrt(768)
#define UNI (1.0f/49.0f)

typedef float f32x4 __attribute__((ext_vector_type(4)));
typedef short bfx8 __attribute__((ext_vector_type(8)));

__device__ __forceinline__ unsigned bfpk(float lo, float hi) {
  unsigned a = __builtin_bit_cast(unsigned, lo);
  unsigned b = __builtin_bit_cast(unsigned, hi);
  a = (a + 0x7fffu + ((a >> 16) & 1u)) >> 16;          // RNE low half
  b = (b + 0x7fffu + ((b >> 16) & 1u)) & 0xffff0000u;  // RNE high half
  return a | b;
}
__device__ __forceinline__ unsigned short bf1(float v) {
  unsigned a = __builtin_bit_cast(unsigned, v);
  return (unsigned short)((a + 0x7fffu + ((a >> 16) & 1u)) >> 16);
}

// raw barrier: waits LDS ops only — global prefetch loads stay in flight
#define BARRIER() do { asm volatile("s_waitcnt lgkmcnt(0)" ::: "memory"); \
                       __builtin_amdgcn_s_barrier(); } while (0)

// ws layout:
//   partL : ushort [ns][b][49][NPIX]   bf16 corr partials
//   partS : float  [ns][b][2][NPIX]    (0: rubin ss, 1: vis ss)
//   invr, invv, dyl, dxl : float [b][NPIX]
//   gacc : float [b][49][144] ; gres : dyg[4], dxg[4]
// out: dra | ddec | conf_local | conf_global[4] | lw

// ---------------- kernel B: banded MFMA correlation ----------------
__global__ __launch_bounds__(1024) void corr_kernel(
    const float* __restrict__ rubin, const float* __restrict__ vis,
    unsigned short* __restrict__ partL, float* __restrict__ partS,
    int KQ, int NCH) {
  __shared__ __align__(16) unsigned short lds[NSLOT*LROW];  // 59,200 B
  __shared__ float ssp[NSLOT*8];                            // 23,680 B
  const int tid = threadIdx.x;
  const int tileX = blockIdx.x % 6, tileY = blockIdx.x / 6;
  const int ns = blockIdx.y, b = blockIdx.z;
  const int k0 = ns * KQ;
  const int g = tid >> 3, q = tid & 7;

  // ---- per-pass staging sources (coalesced: 8 lanes = 128B of one pixel) ----
  const float* src[NPASS];
  int lws[NPASS];
  bool act[NPASS];
  #pragma unroll
  for (int p = 0; p < NPASS; ++p) {
    const int s = p*128 + g;
    act[p] = (s < NSLOT);
    int gh, gw; const float* base;
    if (s < NVIS) {
      const int vy = s / HL, vx = s % HL;
      gh = min(max(tileY*TS + vy - RR, 0), NH-1);
      gw = min(max(tileX*TS + vx - RR, 0), NW-1);
      base = vis;
    } else {
      const int ridx = (s - NVIS) & 255;
      gh = tileY*TS + (ridx >> 4);
      gw = tileX*TS + (ridx & 15);
      base = rubin;
    }
    src[p] = base + ((size_t)(b*NPIX + gh*NW + gw))*ND + (k0 + q*4);
    lws[p] = s*LROW + q*4;     // ushort units; byte = s*80 + q*8
  }

  // ---- MFMA addressing: wave wv owns tile row wv ----
  const int lane = tid & 63, wv = tid >> 6;
  const int j = lane & 15, kq = lane >> 4;
  const int aOff = ABASE + (wv*TS + j)*LROW + kq*8;
  const int bO0 = j*LROW + kq*8;
  const int bO1 = min(j + 16, HL-1)*LROW + kq*8;

  f32x4 acc[7][2];
  #pragma unroll
  for (int dy = 0; dy < 7; ++dy) {
    acc[dy][0] = (f32x4){0.f,0.f,0.f,0.f};
    acc[dy][1] = (f32x4){0.f,0.f,0.f,0.f};
  }
  float ssq[NPASS] = {0.f,0.f,0.f,0.f,0.f,0.f};
  float4 L[NPASS];

  // prologue: chunk 0 loads
  #pragma unroll
  for (int p = 0; p < NPASS; ++p) if (act[p]) L[p] = *(const float4*)(src[p]);

  for (int ch = 0; ch < NCH; ++ch) {
    // write phase: cvt + store chunk ch (compiler inserts vmcnt waits at use)
    #pragma unroll
    for (int p = 0; p < NPASS; ++p) if (act[p]) {
      const float4 v = L[p];
      ssq[p] += v.x*v.x + v.y*v.y + v.z*v.z + v.w*v.w;
      *(uint2*)&lds[lws[p]] = make_uint2(bfpk(v.x,v.y), bfpk(v.z,v.w));
    }
    BARRIER();
    // prefetch chunk ch+1 — stays in flight during MFMA phase
    if (ch + 1 < NCH) {
      #pragma unroll
      for (int p = 0; p < NPASS; ++p) if (act[p])
        L[p] = *(const float4*)(src[p] + (size_t)(ch+1)*DCC);
    }
    // compute phase
    const bfx8 A = *(const bfx8*)&lds[aOff];
    #pragma unroll
    for (int dy = 0; dy < 7; ++dy) {
      const int rbase = (wv + dy)*HL*LROW;
      const bfx8 B0 = *(const bfx8*)&lds[rbase + bO0];
      const bfx8 B1 = *(const bfx8*)&lds[rbase + bO1];
      acc[dy][0] = __builtin_amdgcn_mfma_f32_16x16x32_bf16(A, B0, acc[dy][0], 0, 0, 0);
      acc[dy][1] = __builtin_amdgcn_mfma_f32_16x16x32_bf16(A, B1, acc[dy][1], 0, 0, 0);
    }
    BARRIER();
  }

  // ---- sum-of-squares: VGPR partials -> LDS -> per-pixel reduce ----
  #pragma unroll
  for (int p = 0; p < NPASS; ++p) if (act[p]) ssp[p*1024 + tid] = ssq[p];
  BARRIER();
  if (tid < NSLOT) {
    float ss = 0.f;
    #pragma unroll
    for (int qq = 0; qq < 8; ++qq) ss += ssp[tid*8 + qq];
    float* pS = partS + ((size_t)(ns*NB + b)*2)*NPIX;
    if (tid < NVIS) {
      const int vy = tid / HL, vx = tid % HL;
      if (vy >= RR && vy < HL-RR && vx >= RR && vx < HL-RR)
        pS[(size_t)NPIX + (tileY*TS + vy - RR)*NW + tileX*TS + vx - RR] = ss;
    } else {
      const int ridx = tid - NVIS;
      pS[(tileY*TS + (ridx >> 4))*NW + tileX*TS + (ridx & 15)] = ss;
    }
  }

  // ---- epilogue: scatter valid band entries as bf16 ----
  unsigned short* pL = partL + ((size_t)(ns*NB + b)*NK)*NPIX;
  const int py = tileY*TS + wv, px0 = tileX*TS;
  #pragma unroll
  for (int dy = 0; dy < 7; ++dy)
    #pragma unroll
    for (int h = 0; h < 2; ++h)
      #pragma unroll
      for (int r = 0; r < 4; ++r) {
        const int i = kq*4 + r;
        const int dxp3 = h ? (j + 16 - i) : (j - i);
        if (dxp3 >= 0 && dxp3 < 7)
          pL[(size_t)(dy*7 + dxp3)*NPIX + py*NW + px0 + i] = bf1(acc[dy][h][r]);
      }
}

// ---------------- kernel C0: reduce ss -> inverse norms ----------------
__global__ void norm_kernel(const float* __restrict__ partS, float* __restrict__ invr,
                            float* __restrict__ invv, int NSv) {
  const int g = blockIdx.x*256 + threadIdx.x;
  const int b = g / NPIX, n = g % NPIX;
  float sr = 0.f, sv = 0.f;
  for (int ns = 0; ns < NSv; ++ns) {
    sr += partS[((size_t)(ns*NB + b)*2 + 0)*NPIX + n];
    sv += partS[((size_t)(ns*NB + b)*2 + 1)*NPIX + n];
  }
  invr[g] = 1.f / fmaxf(sqrtf(sr), 1e-6f);
  invv[g] = 1.f / fmaxf(sqrtf(sv), 1e-6f);
}

// ---------------- kernel C: logits + local softmax + global partials ----------------
__global__ __launch_bounds__(256) void local_kernel(
    const unsigned short* __restrict__ partL, const float* __restrict__ invr,
    const float* __restrict__ invv, float* __restrict__ dyl, float* __restrict__ dxl,
    float* __restrict__ gacc, float* __restrict__ out, int NSv) {
  const int g = blockIdx.x*256 + threadIdx.x;
  const int b = g / NPIX, n = g % NPIX;
  const int h = n / NW, w = n % NW;
  const float ir = invr[g] * (SCALE / TAU);
  float t[NK];
  #pragma unroll
  for (int jy = 0; jy < 7; ++jy) {
    #pragma unroll
    for (int jx = 0; jx < 7; ++jx) {
      const int j = jy*7 + jx;
      float c = 0.f;
      for (int ns = 0; ns < NSv; ++ns) {
        const unsigned u = partL[((size_t)(ns*NB + b)*NK + j)*NPIX + n];
        c += __builtin_bit_cast(float, u << 16);
      }
      const int hh = min(max(h + jy - RR, 0), NH-1);
      const int wc = min(max(w + jx - RR, 0), NW-1);
      t[j] = c * ir * invv[b*NPIX + hh*NW + wc];
    }
  }
  const int lane = threadIdx.x & 63;
  const int waveid = (blockIdx.x % 36)*4 + (threadIdx.x >> 6);
  #pragma unroll
  for (int j = 0; j < NK; ++j) {
    float red = t[j];
    #pragma unroll
    for (int m = 1; m < 64; m <<= 1) red += __shfl_xor(red, m);
    if (lane == 0) gacc[((size_t)b*NK + j)*144 + waveid] = red;
  }
  float mx = t[0];
  #pragma unroll
  for (int j = 1; j < NK; ++j) mx = fmaxf(mx, t[j]);
  float s = 0.f, sy = 0.f, sx = 0.f;
  #pragma unroll
  for (int jy = 0; jy < 7; ++jy)
    #pragma unroll
    for (int jx = 0; jx < 7; ++jx) {
      const float e = expf(t[jy*7+jx] - mx);
      s += e; sy += e*(float)(jy-RR); sx += e*(float)(jx-RR);
    }
  const float inv_s = 1.f / s;
  dyl[g] = sy * inv_s;
  dxl[g] = sx * inv_s;
  out[(size_t)2*NB*NPIX + g] = inv_s;
  const float lw = fminf(fmaxf((inv_s - UNI)/(1.f-UNI), 0.f), 1.f);
  out[(size_t)3*NB*NPIX + 4 + g] = lw;
}

// ---------------- kernel D: global softmax per batch ----------------
__global__ void global_kernel(const float* __restrict__ gacc, float* __restrict__ gres,
                              float* __restrict__ out) {
  const int b = blockIdx.x;
  const int k = threadIdx.x;
  float t = -1e30f;
  if (k < NK) {
    float ssum = 0.f;
    for (int i = 0; i < 144; ++i) ssum += gacc[((size_t)b*NK + k)*144 + i];
    t = ssum * (1.f / (float)NPIX);
  }
  float m = t;
  #pragma unroll
  for (int msk = 1; msk < 64; msk <<= 1) m = fmaxf(m, __shfl_xor(m, msk));
  const float e = (k < NK) ? expf(t - m) : 0.f;
  const float dyv = (k < NK) ? (float)(k/7 - RR) : 0.f;
  const float dxv = (k < NK) ? (float)(k%7 - RR) : 0.f;
  float s = e, sy = e*dyv, sx = e*dxv;
  #pragma unroll
  for (int msk = 1; msk < 64; msk <<= 1) {
    s  += __shfl_xor(s,  msk);
    sy += __shfl_xor(sy, msk);
    sx += __shfl_xor(sx, msk);
  }
  if (k == 0) {
    out[(size_t)3*NB*NPIX + b] = 1.f / s;
    gres[b]     = sy / s;
    gres[4 + b] = sx / s;
  }
}

// ---------------- kernel E: blend + 3x3 zero-padded smooth ----------------
__global__ __launch_bounds__(256) void smooth_kernel(
    const float* __restrict__ dyl, const float* __restrict__ dxl,
    const float* __restrict__ gres, float* __restrict__ out,
    const int* __restrict__ hvisp, const int* __restrict__ wvisp) {
  const int g = blockIdx.x*256 + threadIdx.x;
  const int b = g / NPIX, n = g % NPIX;
  const int h = n / NW, w = n % NW;
  const float dyg = gres[b], dxg = gres[4+b];
  const float* conf = out + (size_t)2*NB*NPIX;
  float sy = 0.f, sx = 0.f;
  #pragma unroll
  for (int ddy = -1; ddy <= 1; ++ddy)
    #pragma unroll
    for (int ddx = -1; ddx <= 1; ++ddx) {
      const int hh = h + ddy, wc = w + ddx;
      if (hh >= 0 && hh < NH && wc >= 0 && wc < NW) {
        const int q2 = b*NPIX + hh*NW + wc;
        const float cf = conf[q2];
        const float lw = fminf(fmaxf((cf - UNI)/(1.f-UNI), 0.f), 1.f);
        sy += lw*dyl[q2] + (1.f-lw)*dyg;
        sx += lw*dxl[q2] + (1.f-lw)*dxg;
      }
    }
  const float skyy = (float)hvisp[0] * 0.1f / (float)NH;
  const float skyx = (float)wvisp[0] * 0.1f / (float)NW;
  out[g] = sx * (1.f/9.f) * skyx;
  out[(size_t)NB*NPIX + g] = sy * (1.f/9.f) * skyy;
}

// ---------------- host launch ----------------
extern "C" void kernel_launch(void* const* d_in, const int* in_sizes, int n_in,
                              void* d_out, int out_size, void* d_ws, size_t ws_size,
                              hipStream_t stream) {
  (void)in_sizes; (void)n_in; (void)out_size;
  const float* rubin = (const float*)d_in[0];
  const float* vis   = (const float*)d_in[1];
  const int* hvis = (const int*)d_in[4];
  const int* wvis = (const int*)d_in[5];
  float* out = (float*)d_out;

  // NS split: prefer 8 (finer tail) if workspace allows
  int NSv = 8;
  {
    const size_t need = (size_t)NSv*NB*NK*NPIX*2 + (size_t)NSv*NB*2*NPIX*4
                      + (size_t)4*NB*NPIX*4 + (size_t)NB*NK*144*4 + 64;
    if (ws_size < need) NSv = 4;
  }
  const int KQ = ND / NSv, NCH = KQ / DCC;

  unsigned short* partL = (unsigned short*)d_ws;
  float* partS = (float*)(partL + (size_t)NSv*NB*NK*NPIX);
  float* invr = partS + (size_t)NSv*NB*2*NPIX;
  float* invv = invr + (size_t)NB*NPIX;
  float* dyl  = invv + (size_t)NB*NPIX;
  float* dxl  = dyl  + (size_t)NB*NPIX;
  float* gacc = dxl  + (size_t)NB*NPIX;
  float* gres = gacc + (size_t)NB*NK*144;

  corr_kernel<<<dim3(36, NSv, NB), 1024, 0, stream>>>(rubin, vis, partL, partS, KQ, NCH);
  norm_kernel<<<dim3((NB*NPIX)/256), 256, 0, stream>>>(partS, invr, invv, NSv);
  local_kernel<<<dim3((NB*NPIX)/256), 256, 0, stream>>>(partL, invr, invv, dyl, dxl, gacc, out, NSv);
  global_kernel<<<dim3(NB), 64, 0, stream>>>(gacc, gres, out);
  smooth_kernel<<<dim3((NB*NPIX)/256), 256, 0, stream>>>(dyl, dxl, gres, out, hvis, wvis);
}

// Round 5
// 131.211 us; speedup vs baseline: 1.6377x; 1.6377x over previous
//
#include <hip/hip_runtime.h>
#include <math.h>

// ---------------- problem constants ----------------
#define NB 4
#define NH 96
#define NW 96
#define ND 768
#define NPIX (NH*NW)          // 9216
#define RR 3
#define NK 49
#define NS 4                  // K-split: 4 x 192
#define KQ 192
#define DCC 32                // K per staged chunk
#define NCH 6                 // KQ/DCC
#define TSX 16                // tile 16 wide
#define TSY 4                 //        4 tall (wave per row)
#define HLX 22                // halo 22 wide
#define HLY 10                // halo 10 tall
#define NVIS (HLX*HLY)        // 220
#define VPAD 224              // vis region padded to multiple of 32
#define NSLOT (VPAD+64)       // 288 (224 vis+dummy, 64 rubin)
#define LROW 40               // ushorts per slot (32 bf16 + 8 pad = 80B, 16B-aligned)
#define NPASS 9               // ceil(288*8/256) staging passes
#define TAU 0.1f
#define SCALE 0.03608439182435161f  // 1/sqrt(768)
#define UNI (1.0f/49.0f)

typedef float f32x4 __attribute__((ext_vector_type(4)));
typedef short bfx8 __attribute__((ext_vector_type(8)));
typedef unsigned short u16x8 __attribute__((ext_vector_type(8)));

__device__ __forceinline__ unsigned bfpk(float lo, float hi) {
  unsigned a = __builtin_bit_cast(unsigned, lo);
  unsigned b = __builtin_bit_cast(unsigned, hi);
  a = (a + 0x7fffu + ((a >> 16) & 1u)) >> 16;          // RNE low half
  b = (b + 0x7fffu + ((b >> 16) & 1u)) & 0xffff0000u;  // RNE high half
  return a | b;
}
__device__ __forceinline__ unsigned short bf1(float v) {
  unsigned a = __builtin_bit_cast(unsigned, v);
  return (unsigned short)((a + 0x7fffu + ((a >> 16) & 1u)) >> 16);
}

// barrier that waits LDS ops only (no vmcnt drain)
#define BARRIER() do { asm volatile("s_waitcnt lgkmcnt(0)" ::: "memory"); \
                       __builtin_amdgcn_s_barrier(); } while (0)

// ws layout:
//   partL  : ushort [ns][b][49][NPIX]
//   partS  : float  [ns][b][2][NPIX]   (0: rubin ss, 1: vis ss)
//   logits : float  [b*49][NPIX]       (fp32 sum over ns)
//   invr, invv, dyl, dxl : float [b][NPIX]
//   gacc : float [b][49][144] ; gres : dyg[4], dxg[4]
// out: dra | ddec | conf_local | conf_global[4] | lw

// ---------------- kernel B: banded MFMA correlation ----------------
__global__ __launch_bounds__(256, 4) void corr_kernel(
    const float* __restrict__ rubin, const float* __restrict__ vis,
    unsigned short* __restrict__ partL, float* __restrict__ partS) {
  __shared__ __align__(16) unsigned short lds[NSLOT*LROW];  // 23,040 B
  const int tid = threadIdx.x;
  const int tileX = blockIdx.x % 6, tileY = blockIdx.x / 6;   // 6 x 24 tiles
  const int ns = blockIdx.y, b = blockIdx.z;
  const int k0 = ns * KQ;
  const int g = tid >> 3, q = tid & 7;    // 32 slots/pass, 8 lanes/slot

  // ---- staging slot -> global element offset (32-bit) ----
  unsigned voff[NPASS]; int lws[NPASS];
  #pragma unroll
  for (int p = 0; p < NPASS; ++p) {
    const int s = p*32 + g;
    lws[p] = s*LROW + q*4;
    unsigned pix = 0;
    if (p < 7) {                                 // vis halo (or dummy)
      const int vy = s / HLX, vx = s % HLX;
      const int gh = min(max(tileY*TSY + vy - RR, 0), NH-1);
      const int gw = min(max(tileX*TSX + vx - RR, 0), NW-1);
      pix = (unsigned)(b*NPIX + gh*NW + gw);
    } else {                                     // rubin
      const int ridx = s - VPAD;
      pix = (unsigned)(b*NPIX + (tileY*TSY + (ridx >> 4))*NW + tileX*TSX + (ridx & 15));
    }
    voff[p] = pix*ND + (unsigned)(k0 + q*4);
  }
  // act: pass 6 has only 28 valid groups (slots 192+g < 220)
  #define ACT(p) ((p) != 6 || g < 28)

  // ---- MFMA addressing: wave wv owns tile row wv ----
  const int lane = tid & 63, wv = tid >> 6;
  const int j = lane & 15, kq = lane >> 4;
  const int aOff = (VPAD + wv*TSX + j)*LROW + kq*8;
  const int bO0 = j*LROW + kq*8;
  const int bO1 = min(j + 16, HLX-1)*LROW + kq*8;

  f32x4 acc[7][2];
  #pragma unroll
  for (int dy = 0; dy < 7; ++dy) {
    acc[dy][0] = (f32x4){0.f,0.f,0.f,0.f};
    acc[dy][1] = (f32x4){0.f,0.f,0.f,0.f};
  }
  float ssq[NPASS];
  #pragma unroll
  for (int p = 0; p < NPASS; ++p) ssq[p] = 0.f;

  for (int ch = 0; ch < NCH; ++ch) {
    if (ch) BARRIER();           // prev chunk's MFMA readers done
    #pragma unroll
    for (int p = 0; p < NPASS; ++p) if (ACT(p)) {
      const float4 v = (p < 7)
        ? *(const float4*)(vis   + voff[p] + ch*DCC)
        : *(const float4*)(rubin + voff[p] + ch*DCC);
      ssq[p] += v.x*v.x + v.y*v.y + v.z*v.z + v.w*v.w;
      *(uint2*)&lds[lws[p]] = make_uint2(bfpk(v.x,v.y), bfpk(v.z,v.w));
    }
    BARRIER();
    const bfx8 A = *(const bfx8*)&lds[aOff];
    #pragma unroll
    for (int dy = 0; dy < 7; ++dy) {
      const int rbase = (wv + dy)*HLX*LROW;
      const bfx8 B0 = *(const bfx8*)&lds[rbase + bO0];
      const bfx8 B1 = *(const bfx8*)&lds[rbase + bO1];
      acc[dy][0] = __builtin_amdgcn_mfma_f32_16x16x32_bf16(A, B0, acc[dy][0], 0, 0, 0);
      acc[dy][1] = __builtin_amdgcn_mfma_f32_16x16x32_bf16(A, B1, acc[dy][1], 0, 0, 0);
    }
  }

  // ---- sum-of-squares: reduce across the 8 lanes sharing each slot ----
  float* pS = partS + ((size_t)(ns*NB + b)*2)*NPIX;
  #pragma unroll
  for (int p = 0; p < NPASS; ++p) {
    float r = ACT(p) ? ssq[p] : 0.f;
    r += __shfl_xor(r, 1); r += __shfl_xor(r, 2); r += __shfl_xor(r, 4);
    if (q == 0 && ACT(p)) {
      const int s = p*32 + g;
      if (p < 7) {
        const int vy = s / HLX, vx = s % HLX;
        if (vy >= RR && vy < RR+TSY && vx >= RR && vx < RR+TSX)
          pS[(size_t)NPIX + (tileY*TSY + vy-RR)*NW + tileX*TSX + vx-RR] = r;
      } else {
        const int ridx = s - VPAD;
        pS[(tileY*TSY + (ridx >> 4))*NW + tileX*TSX + (ridx & 15)] = r;
      }
    }
  }

  // ---- epilogue: scatter valid band entries as bf16 ----
  unsigned short* pL = partL + ((size_t)(ns*NB + b)*NK)*NPIX;
  const int py = tileY*TSY + wv, px0 = tileX*TSX;
  #pragma unroll
  for (int dy = 0; dy < 7; ++dy)
    #pragma unroll
    for (int h = 0; h < 2; ++h)
      #pragma unroll
      for (int r = 0; r < 4; ++r) {
        const int i = kq*4 + r;
        const int dxp3 = h ? (j + 16 - i) : (j - i);
        if (dxp3 >= 0 && dxp3 < 7)
          pL[(size_t)(dy*7 + dxp3)*NPIX + py*NW + px0 + i] = bf1(acc[dy][h][r]);
      }
}

// ---------------- kernel C0: reduce ss -> inverse norms ----------------
__global__ void norm_kernel(const float* __restrict__ partS, float* __restrict__ invr,
                            float* __restrict__ invv) {
  const int g = blockIdx.x*256 + threadIdx.x;
  const int b = g / NPIX, n = g % NPIX;
  float sr = 0.f, sv = 0.f;
  #pragma unroll
  for (int ns = 0; ns < NS; ++ns) {
    sr += partS[((size_t)(ns*NB + b)*2 + 0)*NPIX + n];
    sv += partS[((size_t)(ns*NB + b)*2 + 1)*NPIX + n];
  }
  invr[g] = 1.f / fmaxf(sqrtf(sr), 1e-6f);
  invv[g] = 1.f / fmaxf(sqrtf(sv), 1e-6f);
}

// ---------------- kernel C1: sum bf16 partials -> fp32 logits ----------------
__global__ __launch_bounds__(256) void reduce_kernel(
    const unsigned short* __restrict__ partL, float* __restrict__ logits) {
  const int m = blockIdx.x*256 + threadIdx.x;   // 0..225,791
  const int pb = m / (NPIX/8);                  // b*49+j : 0..195
  const int off = (m % (NPIX/8)) * 8;
  float f[8];
  #pragma unroll
  for (int i = 0; i < 8; ++i) f[i] = 0.f;
  #pragma unroll
  for (int ns = 0; ns < NS; ++ns) {
    const u16x8 u = *(const u16x8*)&partL[((size_t)ns*(NB*NK) + pb)*NPIX + off];
    #pragma unroll
    for (int i = 0; i < 8; ++i)
      f[i] += __builtin_bit_cast(float, (unsigned)u[i] << 16);
  }
  float4* dst = (float4*)&logits[(size_t)pb*NPIX + off];
  dst[0] = make_float4(f[0],f[1],f[2],f[3]);
  dst[1] = make_float4(f[4],f[5],f[6],f[7]);
}

// ---------------- kernel C2: logits -> local softmax + global partials ----------------
__global__ __launch_bounds__(256) void local_kernel(
    const float* __restrict__ logits, const float* __restrict__ invr,
    const float* __restrict__ invv, float* __restrict__ dyl, float* __restrict__ dxl,
    float* __restrict__ gacc, float* __restrict__ out) {
  const int g = blockIdx.x*256 + threadIdx.x;
  const int b = g / NPIX, n = g % NPIX;
  const int h = n / NW, w = n % NW;
  const float ir = invr[g] * (SCALE / TAU);
  float t[NK];
  #pragma unroll
  for (int jy = 0; jy < 7; ++jy) {
    #pragma unroll
    for (int jx = 0; jx < 7; ++jx) {
      const int j = jy*7 + jx;
      const float c = logits[((size_t)b*NK + j)*NPIX + n];
      const int hh = min(max(h + jy - RR, 0), NH-1);
      const int wc = min(max(w + jx - RR, 0), NW-1);
      t[j] = c * ir * invv[b*NPIX + hh*NW + wc];
    }
  }
  const int lane = threadIdx.x & 63;
  const int waveid = (blockIdx.x % 36)*4 + (threadIdx.x >> 6);
  #pragma unroll
  for (int j = 0; j < NK; ++j) {
    float red = t[j];
    #pragma unroll
    for (int m = 1; m < 64; m <<= 1) red += __shfl_xor(red, m);
    if (lane == 0) gacc[((size_t)b*NK + j)*144 + waveid] = red;
  }
  float mx = t[0];
  #pragma unroll
  for (int j = 1; j < NK; ++j) mx = fmaxf(mx, t[j]);
  float s = 0.f, sy = 0.f, sx = 0.f;
  #pragma unroll
  for (int jy = 0; jy < 7; ++jy)
    #pragma unroll
    for (int jx = 0; jx < 7; ++jx) {
      const float e = expf(t[jy*7+jx] - mx);
      s += e; sy += e*(float)(jy-RR); sx += e*(float)(jx-RR);
    }
  const float inv_s = 1.f / s;
  dyl[g] = sy * inv_s;
  dxl[g] = sx * inv_s;
  out[(size_t)2*NB*NPIX + g] = inv_s;
  const float lw = fminf(fmaxf((inv_s - UNI)/(1.f-UNI), 0.f), 1.f);
  out[(size_t)3*NB*NPIX + 4 + g] = lw;
}

// ---------------- kernel D: global softmax per batch ----------------
__global__ void global_kernel(const float* __restrict__ gacc, float* __restrict__ gres,
                              float* __restrict__ out) {
  const int b = blockIdx.x;
  const int k = threadIdx.x;
  float t = -1e30f;
  if (k < NK) {
    float ssum = 0.f;
    for (int i = 0; i < 144; ++i) ssum += gacc[((size_t)b*NK + k)*144 + i];
    t = ssum * (1.f / (float)NPIX);
  }
  float m = t;
  #pragma unroll
  for (int msk = 1; msk < 64; msk <<= 1) m = fmaxf(m, __shfl_xor(m, msk));
  const float e = (k < NK) ? expf(t - m) : 0.f;
  const float dyv = (k < NK) ? (float)(k/7 - RR) : 0.f;
  const float dxv = (k < NK) ? (float)(k%7 - RR) : 0.f;
  float s = e, sy = e*dyv, sx = e*dxv;
  #pragma unroll
  for (int msk = 1; msk < 64; msk <<= 1) {
    s  += __shfl_xor(s,  msk);
    sy += __shfl_xor(sy, msk);
    sx += __shfl_xor(sx, msk);
  }
  if (k == 0) {
    out[(size_t)3*NB*NPIX + b] = 1.f / s;
    gres[b]     = sy / s;
    gres[4 + b] = sx / s;
  }
}

// ---------------- kernel E: blend + 3x3 zero-padded smooth ----------------
__global__ __launch_bounds__(256) void smooth_kernel(
    const float* __restrict__ dyl, const float* __restrict__ dxl,
    const float* __restrict__ gres, float* __restrict__ out,
    const int* __restrict__ hvisp, const int* __restrict__ wvisp) {
  const int g = blockIdx.x*256 + threadIdx.x;
  const int b = g / NPIX, n = g % NPIX;
  const int h = n / NW, w = n % NW;
  const float dyg = gres[b], dxg = gres[4+b];
  const float* conf = out + (size_t)2*NB*NPIX;
  float sy = 0.f, sx = 0.f;
  #pragma unroll
  for (int ddy = -1; ddy <= 1; ++ddy)
    #pragma unroll
    for (int ddx = -1; ddx <= 1; ++ddx) {
      const int hh = h + ddy, wc = w + ddx;
      if (hh >= 0 && hh < NH && wc >= 0 && wc < NW) {
        const int q2 = b*NPIX + hh*NW + wc;
        const float cf = conf[q2];
        const float lw = fminf(fmaxf((cf - UNI)/(1.f-UNI), 0.f), 1.f);
        sy += lw*dyl[q2] + (1.f-lw)*dyg;
        sx += lw*dxl[q2] + (1.f-lw)*dxg;
      }
    }
  const float skyy = (float)hvisp[0] * 0.1f / (float)NH;
  const float skyx = (float)wvisp[0] * 0.1f / (float)NW;
  out[g] = sx * (1.f/9.f) * skyx;
  out[(size_t)NB*NPIX + g] = sy * (1.f/9.f) * skyy;
}

// ---------------- host launch ----------------
extern "C" void kernel_launch(void* const* d_in, const int* in_sizes, int n_in,
                              void* d_out, int out_size, void* d_ws, size_t ws_size,
                              hipStream_t stream) {
  (void)in_sizes; (void)n_in; (void)out_size; (void)ws_size;
  const float* rubin = (const float*)d_in[0];
  const float* vis   = (const float*)d_in[1];
  const int* hvis = (const int*)d_in[4];
  const int* wvis = (const int*)d_in[5];
  float* out = (float*)d_out;

  unsigned short* partL = (unsigned short*)d_ws;               // NS*NB*49*NPIX u16
  float* partS  = (float*)(partL + (size_t)NS*NB*NK*NPIX);     // NS*NB*2*NPIX f32
  float* logits = partS + (size_t)NS*NB*2*NPIX;                // NB*49*NPIX f32
  float* invr = logits + (size_t)NB*NK*NPIX;
  float* invv = invr + (size_t)NB*NPIX;
  float* dyl  = invv + (size_t)NB*NPIX;
  float* dxl  = dyl  + (size_t)NB*NPIX;
  float* gacc = dxl  + (size_t)NB*NPIX;
  float* gres = gacc + (size_t)NB*NK*144;

  corr_kernel<<<dim3(144, NS, NB), 256, 0, stream>>>(rubin, vis, partL, partS);
  norm_kernel<<<dim3((NB*NPIX)/256), 256, 0, stream>>>(partS, invr, invv);
  reduce_kernel<<<dim3((NB*NK*NPIX/8)/256), 256, 0, stream>>>(partL, logits);
  local_kernel<<<dim3((NB*NPIX)/256), 256, 0, stream>>>(logits, invr, invv, dyl, dxl, gacc, out);
  global_kernel<<<dim3(NB), 64, 0, stream>>>(gacc, gres, out);
  smooth_kernel<<<dim3((NB*NPIX)/256), 256, 0, stream>>>(dyl, dxl, gres, out, hvis, wvis);
}